// Round 8
// baseline (113.425 us; speedup 1.0000x reference)
//
#include <hip/hip_runtime.h>

// CVXPolicy_Quadcopter: fused MLP (13->100 tanh ->12) + closed-form argmin via
// Lambert W. 2 elements/thread x hidden-unit PAIRS (v_pk_fma_f32).
// R7: broadcast input pairs are materialized ONCE into vf2 arrays before the
// jp-loop (R4 showed VGPR=20 => compiler was re-materializing ~26 v_movs/iter
// inside the loop). Tanh finish is swizzle-free (no vf2 lane swaps).
// ws layout (pack_weights):
//   region A: 50 rows x 32 floats: [pair(k=0)..pair(k=12), pair(b1'), pad x4]
//     (W1, b1 pre-scaled by 2*log2e so tanh uses exp2 with no multiply)
//   region B (+1600): 50 rows x 16 floats: [pair(m=0)..pair(m=5), pad x4]

constexpr int S = 12;   // z features
constexpr int H = 100;  // hidden
#define TWO_LOG2E 2.8853900817779268f

typedef float vf2 __attribute__((ext_vector_type(2)));

__device__ __forceinline__ float fast_rcp(float x) {
    return __builtin_amdgcn_rcpf(x);
}

__global__ __launch_bounds__(256) void pack_weights(
    const float* __restrict__ W1, const float* __restrict__ b1,
    const float* __restrict__ W2, float* __restrict__ ws)
{
    int idx = blockIdx.x * 256 + threadIdx.x;
    if (idx < 1600) {                        // region A: jp = idx/32, s = idx%32
        int jp = idx >> 5, s = idx & 31;
        float v = 0.0f;
        if (s < 26) {
            int k = s >> 1, half = s & 1;
            v = W1[k * H + 2 * jp + half] * TWO_LOG2E;
        } else if (s < 28) {
            int half = s & 1;
            v = b1[2 * jp + half] * TWO_LOG2E;
        }
        ws[idx] = v;
    } else if (idx < 2400) {                 // region B: jp = r/16, s = r%16
        int r = idx - 1600;
        int jp = r >> 4, s = r & 15;
        float v = 0.0f;
        if (s < 12) {
            int m = s >> 1, half = s & 1;
            v = W2[(2 * jp + half) * S + 6 + m];
        }
        ws[idx] = v;
    }
}

__global__ __launch_bounds__(256) void cvx_quad_kernel(
    const float* __restrict__ z, const float* __restrict__ t,
    const float* __restrict__ ws, const float* __restrict__ b2,
    float* __restrict__ out, int B)
{
    int tid = blockIdx.x * 256 + threadIdx.x;
    int i0 = tid * 2;
    if (i0 >= B) return;
    int i1 = (i0 + 1 < B) ? (i0 + 1) : (B - 1);   // odd-B safe

    // ---- load two input rows and materialize broadcast pairs ONCE ----
    vf2 iA[S + 1], iB[S + 1];
    {
        float f;
        f = t[i0]; iA[0] = (vf2){f, f};
        f = t[i1]; iB[0] = (vf2){f, f};
        const float4* zr0 = reinterpret_cast<const float4*>(z) + (size_t)i0 * 3;
        const float4* zr1 = reinterpret_cast<const float4*>(z) + (size_t)i1 * 3;
        float4 a0 = zr0[0], a1 = zr0[1], a2 = zr0[2];
        float4 d0 = zr1[0], d1 = zr1[1], d2 = zr1[2];
        iA[1]  = (vf2){a0.x, a0.x}; iA[2]  = (vf2){a0.y, a0.y};
        iA[3]  = (vf2){a0.z, a0.z}; iA[4]  = (vf2){a0.w, a0.w};
        iA[5]  = (vf2){a1.x, a1.x}; iA[6]  = (vf2){a1.y, a1.y};
        iA[7]  = (vf2){a1.z, a1.z}; iA[8]  = (vf2){a1.w, a1.w};
        iA[9]  = (vf2){a2.x, a2.x}; iA[10] = (vf2){a2.y, a2.y};
        iA[11] = (vf2){a2.z, a2.z}; iA[12] = (vf2){a2.w, a2.w};
        iB[1]  = (vf2){d0.x, d0.x}; iB[2]  = (vf2){d0.y, d0.y};
        iB[3]  = (vf2){d0.z, d0.z}; iB[4]  = (vf2){d0.w, d0.w};
        iB[5]  = (vf2){d1.x, d1.x}; iB[6]  = (vf2){d1.y, d1.y};
        iB[7]  = (vf2){d1.z, d1.z}; iB[8]  = (vf2){d1.w, d1.w};
        iB[9]  = (vf2){d2.x, d2.x}; iB[10] = (vf2){d2.y, d2.y};
        iB[11] = (vf2){d2.z, d2.z}; iB[12] = (vf2){d2.w, d2.w};
    }

    // pk accumulators for p[6..11], both elements
    vf2 pA[6], pB[6];
    #pragma unroll
    for (int m = 0; m < 6; ++m) {
        float bm = b2[6 + m];
        pA[m] = (vf2){bm, 0.0f};
        pB[m] = (vf2){bm, 0.0f};
    }

    #pragma unroll 2
    for (int jp = 0; jp < H / 2; ++jp) {
        const vf2* wrow = reinterpret_cast<const vf2*>(ws + jp * 32);
        vf2 bias = wrow[13];                 // (b1'_j, b1'_j1), pre-scaled
        vf2 accA = bias, accB = bias;
        #pragma unroll
        for (int k = 0; k < S + 1; ++k) {    // 2x 13 v_pk_fma_f32, shared wrow
            vf2 w = wrow[k];
            accA = __builtin_elementwise_fma(iA[k], w, accA);
            accB = __builtin_elementwise_fma(iB[k], w, accB);
        }

        // tanh(y), acc = 2*log2e*y: e = 2^acc; th = 1 - 2/(1+e)
        // pairwise shared rcp, swizzle-free: s = -2*rcp(a*b);
        // th0 = fma(b, s, 1); th1 = fma(a, s, 1)
        float aA = 1.0f + __builtin_amdgcn_exp2f(accA.x);
        float bA = 1.0f + __builtin_amdgcn_exp2f(accA.y);
        float aB = 1.0f + __builtin_amdgcn_exp2f(accB.x);
        float bB = 1.0f + __builtin_amdgcn_exp2f(accB.y);
        float sA = -2.0f * fast_rcp(aA * bA);
        float sB = -2.0f * fast_rcp(aB * bB);
        vf2 thA, thB;
        thA.x = fmaf(bA, sA, 1.0f);
        thA.y = fmaf(aA, sA, 1.0f);
        thB.x = fmaf(bB, sB, 1.0f);
        thB.y = fmaf(aB, sB, 1.0f);

        const vf2* qrow = reinterpret_cast<const vf2*>(ws + 1600 + jp * 16);
        #pragma unroll
        for (int m = 0; m < 6; ++m) {        // 2x 6 v_pk_fma_f32, shared qrow
            vf2 q = qrow[m];
            pA[m] = __builtin_elementwise_fma(thA, q, pA[m]);
            pB[m] = __builtin_elementwise_fma(thB, q, pB[m]);
        }
    }

    #pragma unroll
    for (int e = 0; e < 2; ++e) {
        const vf2* p = e ? pB : pA;
        float p0 = p[0].x + p[0].y, p1 = p[1].x + p[1].y, p2 = p[2].x + p[2].y;
        float p3 = p[3].x + p[3].y, p4 = p[4].x + p[4].y, p5 = p[5].x + p[5].y;

        float c0 = 2.0f * (p0 + p1 + p2);  // / MASS, MASS = 0.5
        float c1 = p3, c2 = p4, c3 = p5;
        float x = fmaf(c0, c0, fmaf(c1, c1, fmaf(c2, c2, c3 * c3)));

        // Lambert W: solve w e^w = x, Newton from w0 = log(1+x)
        float w = __logf(1.0f + x);
        #pragma unroll
        for (int it = 0; it < 5; ++it) {
            float ew  = __expf(w);
            float num = fmaf(w, ew, -x);        // w*e^w - x
            float den = fmaf(ew, w, ew);        // e^w * (w + 1)
            w = w - num * fast_rcp(den);
        }

        float sc = -__expf(-0.5f * w);
        float4 o;
        o.x = c0 * sc;
        o.y = c1 * sc;
        o.z = c2 * sc;
        o.w = c3 * sc;
        reinterpret_cast<float4*>(out)[e ? i1 : i0] = o;
    }
}

extern "C" void kernel_launch(void* const* d_in, const int* in_sizes, int n_in,
                              void* d_out, int out_size, void* d_ws, size_t ws_size,
                              hipStream_t stream) {
    const float* z  = (const float*)d_in[0];
    const float* t  = (const float*)d_in[1];
    const float* W1 = (const float*)d_in[2];
    const float* b1 = (const float*)d_in[3];
    const float* W2 = (const float*)d_in[4];
    const float* b2 = (const float*)d_in[5];
    float* out = (float*)d_out;
    float* ws  = (float*)d_ws;      // needs 2400 floats = 9.6 KB

    pack_weights<<<dim3(10), dim3(256), 0, stream>>>(W1, b1, W2, ws);

    int B = in_sizes[1];  // t has B elements
    int threads = (B + 1) / 2;
    int grid = (threads + 255) / 256;
    cvx_quad_kernel<<<dim3(grid), dim3(256), 0, stream>>>(z, t, ws, b2, out, B);
}

// Round 10
// 104.779 us; speedup vs baseline: 1.0825x; 1.0825x over previous
//
#include <hip/hip_runtime.h>

// CVXPolicy_Quadcopter: fused MLP (13->100 tanh ->12) + closed-form argmin via
// Lambert W. 2 elements/thread; layer-1/2 MACs via v_dot2_f32_f16 (full-rate
// 2 f16 MAC / 2-cyc inst, f32 accumulate). gfx950 packed fp32 (v_pk_fma_f32)
// is HALF-RATE per component (157.3 TF peak is unpacked) -- R4/R6 pk math
// bought nothing; dot2 halves true FMA issue.
// ws layout (uint32 dwords, built by pack_weights):
//   region A [0..799]:  per unit-pair jp (16 dw):
//     dw 0..6  : half2 W1' k-pairs (k=2s,2s+1; k=13 pad=0) for unit 2jp
//     dw 7..13 : same for unit 2jp+1
//     dw 14,15 : float b1'[2jp], b1'[2jp+1]
//     (W1', b1' pre-scaled by 2*log2e so tanh uses exp2 with no multiply)
//   region B [800..1199]: per jp (8 dw): dw m=0..5: half2 {W2[2jp][6+m],
//     W2[2jp+1][6+m]}; dw 6,7 pad

constexpr int S = 12;   // z features
constexpr int H = 100;  // hidden
#define TWO_LOG2E 2.8853900817779268f

typedef _Float16 h2 __attribute__((ext_vector_type(2)));

__device__ __forceinline__ float fast_rcp(float x) {
    return __builtin_amdgcn_rcpf(x);
}

__device__ __forceinline__ h2 bit_h2(unsigned int u) {
    union { unsigned int u; h2 h; } cv; cv.u = u; return cv.h;
}

#if __has_builtin(__builtin_amdgcn_fdot2)
__device__ __forceinline__ float fdot2(h2 a, h2 b, float c) {
    return __builtin_amdgcn_fdot2(a, b, c, false);
}
#else
__device__ __forceinline__ float fdot2(h2 a, h2 b, float c) {
    return fmaf((float)a.x, (float)b.x, fmaf((float)a.y, (float)b.y, c));
}
#endif

// v_cvt_pkrtz_f16_f32: pack two f32 -> half2 (round toward zero).
// Builtin returns __fp16 vector; bitcast to our _Float16 vector.
__device__ __forceinline__ h2 pk16(float a, float b) {
#if __has_builtin(__builtin_amdgcn_cvt_pkrtz)
    union {
        __fp16 __attribute__((ext_vector_type(2))) f;
        h2 h;
    } cv;
    cv.f = __builtin_amdgcn_cvt_pkrtz(a, b);
    return cv.h;
#else
    h2 r; r.x = (_Float16)a; r.y = (_Float16)b; return r;
#endif
}

__global__ __launch_bounds__(256) void pack_weights(
    const float* __restrict__ W1, const float* __restrict__ b1,
    const float* __restrict__ W2, unsigned int* __restrict__ ws)
{
    int idx = blockIdx.x * 256 + threadIdx.x;
    if (idx < 800) {                         // region A
        int jp = idx >> 4, s = idx & 15;
        unsigned int v;
        if (s < 14) {
            int unit = 2 * jp + (s >= 7);
            int q = (s < 7) ? s : s - 7;
            int k0 = 2 * q, k1 = 2 * q + 1;
            float w0 = W1[k0 * H + unit] * TWO_LOG2E;
            float w1 = (k1 < 13) ? W1[k1 * H + unit] * TWO_LOG2E : 0.0f;
            union { h2 h; unsigned int u; } cv;
            cv.h = pk16(w0, w1);
            v = cv.u;
        } else {
            int unit = 2 * jp + (s - 14);
            union { float f; unsigned int u; } cv;
            cv.f = b1[unit] * TWO_LOG2E;
            v = cv.u;
        }
        ws[idx] = v;
    } else if (idx < 1200) {                 // region B
        int r = idx - 800;
        int jp = r >> 3, m = r & 7;
        unsigned int v = 0;
        if (m < 6) {
            float w0 = W2[(2 * jp) * S + 6 + m];
            float w1 = W2[(2 * jp + 1) * S + 6 + m];
            union { h2 h; unsigned int u; } cv;
            cv.h = pk16(w0, w1);
            v = cv.u;
        }
        ws[idx] = v;
    }
}

__global__ __launch_bounds__(256) void cvx_quad_kernel(
    const float* __restrict__ z, const float* __restrict__ t,
    const unsigned int* __restrict__ ws, const float* __restrict__ b2,
    float* __restrict__ out, int B)
{
    int tid = blockIdx.x * 256 + threadIdx.x;
    int i0 = tid * 2;
    if (i0 >= B) return;
    int i1 = (i0 + 1 < B) ? (i0 + 1) : (B - 1);   // odd-B safe

    // ---- load two input rows, convert to half2 k-pairs once ----
    h2 inA[7], inB[7];
    {
        const float4* zr0 = reinterpret_cast<const float4*>(z) + (size_t)i0 * 3;
        const float4* zr1 = reinterpret_cast<const float4*>(z) + (size_t)i1 * 3;
        float4 a0 = zr0[0], a1 = zr0[1], a2 = zr0[2];
        float4 d0 = zr1[0], d1 = zr1[1], d2 = zr1[2];
        inA[0] = pk16(t[i0], a0.x);
        inA[1] = pk16(a0.y, a0.z);
        inA[2] = pk16(a0.w, a1.x);
        inA[3] = pk16(a1.y, a1.z);
        inA[4] = pk16(a1.w, a2.x);
        inA[5] = pk16(a2.y, a2.z);
        inA[6] = pk16(a2.w, 0.0f);
        inB[0] = pk16(t[i1], d0.x);
        inB[1] = pk16(d0.y, d0.z);
        inB[2] = pk16(d0.w, d1.x);
        inB[3] = pk16(d1.y, d1.z);
        inB[4] = pk16(d1.w, d2.x);
        inB[5] = pk16(d2.y, d2.z);
        inB[6] = pk16(d2.w, 0.0f);
    }

    // f32 accumulators for p[6..11], both elements
    float pA[6], pB[6];
    #pragma unroll
    for (int m = 0; m < 6; ++m) {
        float bm = b2[6 + m];
        pA[m] = bm;
        pB[m] = bm;
    }

    #pragma unroll 2
    for (int jp = 0; jp < H / 2; ++jp) {
        const unsigned int* ra = ws + jp * 16;
        const unsigned int* rb = ws + 800 + jp * 8;

        float fb0 = __uint_as_float(ra[14]);
        float fb1 = __uint_as_float(ra[15]);
        float accA0 = fb0, accA1 = fb1, accB0 = fb0, accB1 = fb1;
        #pragma unroll
        for (int q = 0; q < 7; ++q) {        // 4x7 v_dot2_f32_f16
            h2 w0 = bit_h2(ra[q]);
            h2 w1 = bit_h2(ra[7 + q]);
            accA0 = fdot2(inA[q], w0, accA0);
            accA1 = fdot2(inA[q], w1, accA1);
            accB0 = fdot2(inB[q], w0, accB0);
            accB1 = fdot2(inB[q], w1, accB1);
        }

        // tanh(y), acc = 2*log2e*y: e = 2^acc; th = 1 - 2/(1+e)
        // shared rcp per unit-pair: r = rcp(a0*a1); 1/a0 = a1*r
        float aA0 = 1.0f + __builtin_amdgcn_exp2f(accA0);
        float aA1 = 1.0f + __builtin_amdgcn_exp2f(accA1);
        float aB0 = 1.0f + __builtin_amdgcn_exp2f(accB0);
        float aB1 = 1.0f + __builtin_amdgcn_exp2f(accB1);
        float sA = -2.0f * fast_rcp(aA0 * aA1);
        float sB = -2.0f * fast_rcp(aB0 * aB1);
        float thA0 = fmaf(aA1, sA, 1.0f);
        float thA1 = fmaf(aA0, sA, 1.0f);
        float thB0 = fmaf(aB1, sB, 1.0f);
        float thB1 = fmaf(aB0, sB, 1.0f);
        h2 tA = pk16(thA0, thA1);
        h2 tB = pk16(thB0, thB1);

        #pragma unroll
        for (int m = 0; m < 6; ++m) {        // 2x6 v_dot2_f32_f16
            h2 qm = bit_h2(rb[m]);
            pA[m] = fdot2(tA, qm, pA[m]);
            pB[m] = fdot2(tB, qm, pB[m]);
        }
    }

    #pragma unroll
    for (int e = 0; e < 2; ++e) {
        const float* p = e ? pB : pA;
        float c0 = 2.0f * (p[0] + p[1] + p[2]);  // / MASS, MASS = 0.5
        float c1 = p[3], c2 = p[4], c3 = p[5];
        float x = fmaf(c0, c0, fmaf(c1, c1, fmaf(c2, c2, c3 * c3)));

        // Lambert W: solve w e^w = x, Newton from w0 = log(1+x)
        float w = __logf(1.0f + x);
        #pragma unroll
        for (int it = 0; it < 5; ++it) {
            float ew  = __expf(w);
            float num = fmaf(w, ew, -x);        // w*e^w - x
            float den = fmaf(ew, w, ew);        // e^w * (w + 1)
            w = w - num * fast_rcp(den);
        }

        float sc = -__expf(-0.5f * w);
        float4 o;
        o.x = c0 * sc;
        o.y = c1 * sc;
        o.z = c2 * sc;
        o.w = c3 * sc;
        reinterpret_cast<float4*>(out)[e ? i1 : i0] = o;
    }
}

extern "C" void kernel_launch(void* const* d_in, const int* in_sizes, int n_in,
                              void* d_out, int out_size, void* d_ws, size_t ws_size,
                              hipStream_t stream) {
    const float* z  = (const float*)d_in[0];
    const float* t  = (const float*)d_in[1];
    const float* W1 = (const float*)d_in[2];
    const float* b1 = (const float*)d_in[3];
    const float* W2 = (const float*)d_in[4];
    const float* b2 = (const float*)d_in[5];
    float* out = (float*)d_out;
    unsigned int* ws = (unsigned int*)d_ws;   // needs 1200 dwords = 4.8 KB

    pack_weights<<<dim3(5), dim3(256), 0, stream>>>(W1, b1, W2, ws);

    int B = in_sizes[1];  // t has B elements
    int threads = (B + 1) / 2;
    int grid = (threads + 255) / 256;
    cvx_quad_kernel<<<dim3(grid), dim3(256), 0, stream>>>(z, t, ws, b2, out, B);
}